// Round 2
// baseline (670.902 us; speedup 1.0000x reference)
//
#include <hip/hip_runtime.h>
#include <math.h>

#define NN   8192
#define KK   16
#define DD   64
#define SS   8
#define BB   64
#define HH   4
#define FF   576
#define HIDD 64
#define FH   144   // FF / HH

__device__ __forceinline__ float gelu_tanh(float x) {
    const float c0 = 0.7978845608028654f;  // sqrt(2/pi)
    const float c1 = 0.044715f;
    float inner = c0 * (x + c1 * x * x * x);
    return 0.5f * x * (1.0f + tanhf(inner));
}

__global__ __launch_bounds__(256) void fused_node_attn(
    const float* __restrict__ node_feat,
    const float* __restrict__ edge_sh,
    const float* __restrict__ edge_inv,
    const float* __restrict__ cutoff,
    const float* __restrict__ Wk1,
    const float* __restrict__ Wk2,
    const float* __restrict__ Wk3,
    const float* __restrict__ Wv1,
    const float* __restrict__ Wv2,
    const float* __restrict__ Wv3,
    const float* __restrict__ Wlogit,
    const float* __restrict__ Wout,
    const int*  __restrict__ edge_src,
    float* __restrict__ out)
{
    const int n    = blockIdx.x;
    const int tid  = threadIdx.x;
    const int lane = tid & 63;
    const int wid  = tid >> 6;

    __shared__ float s_q[DD];
    __shared__ float s_x[KK][DD];
    __shared__ float s_sh[KK][SS];
    __shared__ float s_shsq[KK][SS];
    __shared__ float s_inv[KK][BB];
    __shared__ float s_cut[KK];
    __shared__ int   s_src[KK];
    __shared__ float s_h1[2][KK][HIDD];
    __shared__ float s_h2[2][KK][HIDD];
    __shared__ float s_logit[KK][HH];
    __shared__ float s_wgt[KK][HH];
    __shared__ float s_acc[FF];
    __shared__ float s_red[4][DD];

    // ---------------- load inputs ----------------
    if (tid < KK) {
        s_src[tid] = edge_src[n * KK + tid];
        s_cut[tid] = cutoff[n * KK + tid];
    }
    if (tid < DD) s_q[tid] = node_feat[(size_t)n * DD + tid];
    if (tid < KK * SS) {
        int e = tid >> 3, s = tid & 7;
        float v = edge_sh[(size_t)(n * KK + e) * SS + s];
        s_sh[e][s]   = v;
        s_shsq[e][s] = v * v;
    }
    // edge_inv: 16 edges x 64 floats = 256 float4, one per thread
    {
        float4 v = reinterpret_cast<const float4*>(edge_inv + (size_t)n * KK * BB)[tid];
        reinterpret_cast<float4*>(&s_inv[0][0])[tid] = v;
    }
    __syncthreads();
    // x_src gather: 16 edges x 16 float4
    {
        int e = tid >> 4, f4 = tid & 15;
        float4 v = reinterpret_cast<const float4*>(node_feat + (size_t)s_src[e] * DD)[f4];
        reinterpret_cast<float4*>(&s_x[e][0])[f4] = v;
    }
    __syncthreads();

    // ---------------- layer 1 (k & v MLPs) ----------------
    {
        const int e0 = wid * 4;
#pragma unroll
        for (int mat = 0; mat < 2; ++mat) {
            const float* W = (mat == 0) ? Wk1 : Wv1;
            float a0 = 0.f, a1 = 0.f, a2 = 0.f, a3 = 0.f;
            for (int k = 0; k < BB; ++k) {
                float w = W[k * HIDD + lane];
                a0 = fmaf(s_inv[e0 + 0][k], w, a0);
                a1 = fmaf(s_inv[e0 + 1][k], w, a1);
                a2 = fmaf(s_inv[e0 + 2][k], w, a2);
                a3 = fmaf(s_inv[e0 + 3][k], w, a3);
            }
            s_h1[mat][e0 + 0][lane] = gelu_tanh(a0);
            s_h1[mat][e0 + 1][lane] = gelu_tanh(a1);
            s_h1[mat][e0 + 2][lane] = gelu_tanh(a2);
            s_h1[mat][e0 + 3][lane] = gelu_tanh(a3);
        }
    }
    __syncthreads();

    // ---------------- layer 2 ----------------
    {
        const int e0 = wid * 4;
#pragma unroll
        for (int mat = 0; mat < 2; ++mat) {
            const float* W = (mat == 0) ? Wk2 : Wv2;
            float a0 = 0.f, a1 = 0.f, a2 = 0.f, a3 = 0.f;
            for (int k = 0; k < HIDD; ++k) {
                float w = W[k * HIDD + lane];
                a0 = fmaf(s_h1[mat][e0 + 0][k], w, a0);
                a1 = fmaf(s_h1[mat][e0 + 1][k], w, a1);
                a2 = fmaf(s_h1[mat][e0 + 2][k], w, a2);
                a3 = fmaf(s_h1[mat][e0 + 3][k], w, a3);
            }
            s_h2[mat][e0 + 0][lane] = gelu_tanh(a0);
            s_h2[mat][e0 + 1][lane] = gelu_tanh(a1);
            s_h2[mat][e0 + 2][lane] = gelu_tanh(a2);
            s_h2[mat][e0 + 3][lane] = gelu_tanh(a3);
        }
    }
    __syncthreads();

    // ---------------- k path: layer-3(k) + logits ----------------
    // lane = d.  g[d] = sum_k h2k[k]*Wk3[k][d]
    //            t[d] = sum_k h2k[k]*sum_s sh^2[s]*Wk3[k][64+8d+s]
    {
        const int e0 = wid * 4;
        float sq[4][SS];
#pragma unroll
        for (int ee = 0; ee < 4; ++ee)
#pragma unroll
            for (int s = 0; s < SS; ++s) sq[ee][s] = s_shsq[e0 + ee][s];

        float g[4] = {0.f, 0.f, 0.f, 0.f};
        float t[4] = {0.f, 0.f, 0.f, 0.f};
        for (int k = 0; k < HIDD; ++k) {
            const float* row = Wk3 + (size_t)k * FF;
            float wg = row[lane];
            float4 wa = *reinterpret_cast<const float4*>(row + DD + 8 * lane);
            float4 wb = *reinterpret_cast<const float4*>(row + DD + 8 * lane + 4);
#pragma unroll
            for (int ee = 0; ee < 4; ++ee) {
                float hh = s_h2[0][e0 + ee][k];
                g[ee] = fmaf(hh, wg, g[ee]);
                float tk = 0.f;
                tk = fmaf(sq[ee][0], wa.x, tk);
                tk = fmaf(sq[ee][1], wa.y, tk);
                tk = fmaf(sq[ee][2], wa.z, tk);
                tk = fmaf(sq[ee][3], wa.w, tk);
                tk = fmaf(sq[ee][4], wb.x, tk);
                tk = fmaf(sq[ee][5], wb.y, tk);
                tk = fmaf(sq[ee][6], wb.z, tk);
                tk = fmaf(sq[ee][7], wb.w, tk);
                t[ee] = fmaf(hh, tk, t[ee]);
            }
        }
        // W_logit rows (2*D x H), H=4 -> one float4 per row
        float4 wl0 = reinterpret_cast<const float4*>(Wlogit)[lane];
        float4 wl1 = reinterpret_cast<const float4*>(Wlogit)[DD + lane];
        float qd = s_q[lane];
#pragma unroll
        for (int ee = 0; ee < 4; ++ee) {
            float qx = qd * s_x[e0 + ee][lane];
            float a0 = qx * g[ee];
            float a1 = qx * t[ee];
            float p0 = a0 * wl0.x + a1 * wl1.x;
            float p1 = a0 * wl0.y + a1 * wl1.y;
            float p2 = a0 * wl0.z + a1 * wl1.z;
            float p3 = a0 * wl0.w + a1 * wl1.w;
#pragma unroll
            for (int off = 32; off >= 1; off >>= 1) {
                p0 += __shfl_xor(p0, off, 64);
                p1 += __shfl_xor(p1, off, 64);
                p2 += __shfl_xor(p2, off, 64);
                p3 += __shfl_xor(p3, off, 64);
            }
            if (lane == 0) {
                s_logit[e0 + ee][0] = p0;
                s_logit[e0 + ee][1] = p1;
                s_logit[e0 + ee][2] = p2;
                s_logit[e0 + ee][3] = p3;
            }
        }
    }
    __syncthreads();

    // ---------------- softmax over the 16 edges, per head ----------------
    if (tid < HH) {
        const int h = tid;
        float m = -1e30f;
        for (int e = 0; e < KK; ++e) m = fmaxf(m, s_logit[e][h]);
        float ex[KK];
        float z = 0.f;
        for (int e = 0; e < KK; ++e) {
            ex[e] = s_cut[e] * expf(s_logit[e][h] - m);
            z += ex[e];
        }
        if (z == 0.f) z = 1.f;
        float inv_z = 1.f / z;
        for (int e = 0; e < KK; ++e) {
            float a = ex[e] * inv_z;
            s_wgt[e][h] = sqrtf(a > 0.f ? a : 0.f);  // sqrt(relu(alpha))
        }
    }
    __syncthreads();

    // ---------------- v path: layer-3(v) * out1 * w, summed over edges ----------------
    for (int c = tid; c < FF; c += 256) {
        float acc[KK];
#pragma unroll
        for (int e = 0; e < KK; ++e) acc[e] = 0.f;
        for (int k = 0; k < HIDD; ++k) {
            float w = Wv3[(size_t)k * FF + c];
#pragma unroll
            for (int e = 0; e < KK; ++e) acc[e] = fmaf(s_h2[1][e][k], w, acc[e]);
        }
        const int hidx = c / FH;
        float total = 0.f;
        if (c < DD) {
#pragma unroll
            for (int e = 0; e < KK; ++e)
                total += s_x[e][c] * acc[e] * s_wgt[e][hidx];
        } else {
            const int d = (c - DD) >> 3, s = (c - DD) & 7;
#pragma unroll
            for (int e = 0; e < KK; ++e)
                total += s_x[e][d] * s_sh[e][s] * acc[e] * s_wgt[e][hidx];
        }
        s_acc[c] = total;
    }
    __syncthreads();

    // ---------------- final projection: node_out @ W_out ----------------
    {
        float p = 0.f;
        const int j0 = wid * FH;
        for (int j = j0; j < j0 + FH; ++j)
            p = fmaf(s_acc[j], Wout[(size_t)j * DD + lane], p);
        s_red[wid][lane] = p;
    }
    __syncthreads();
    if (tid < DD) {
        float r = s_red[0][tid] + s_red[1][tid] + s_red[2][tid] + s_red[3][tid];
        out[(size_t)n * DD + tid] = r;
    }
}

extern "C" void kernel_launch(void* const* d_in, const int* in_sizes, int n_in,
                              void* d_out, int out_size, void* d_ws, size_t ws_size,
                              hipStream_t stream) {
    const float* node_feat = (const float*)d_in[0];
    const float* edge_sh   = (const float*)d_in[1];
    const float* edge_inv  = (const float*)d_in[2];
    const float* cutoff    = (const float*)d_in[3];
    const float* Wk1       = (const float*)d_in[4];
    const float* Wk2       = (const float*)d_in[5];
    const float* Wk3       = (const float*)d_in[6];
    const float* Wv1       = (const float*)d_in[7];
    const float* Wv2       = (const float*)d_in[8];
    const float* Wv3       = (const float*)d_in[9];
    const float* Wlogit    = (const float*)d_in[10];
    const float* Wout      = (const float*)d_in[11];
    const int*   edge_src  = (const int*)d_in[12];
    float* out = (float*)d_out;

    fused_node_attn<<<NN, 256, 0, stream>>>(
        node_feat, edge_sh, edge_inv, cutoff,
        Wk1, Wk2, Wk3, Wv1, Wv2, Wv3,
        Wlogit, Wout, edge_src, out);
}

// Round 3
// 235.310 us; speedup vs baseline: 2.8511x; 2.8511x over previous
//
#include <hip/hip_runtime.h>
#include <math.h>

typedef unsigned short u16;
typedef short bf16x8 __attribute__((ext_vector_type(8)));
typedef unsigned short u16x4 __attribute__((ext_vector_type(4)));
typedef float f32x4 __attribute__((ext_vector_type(4)));

#define MFMA(a,b,c) __builtin_amdgcn_mfma_f32_16x16x32_bf16((a),(b),(c),0,0,0)

// ws layout (u16 elements): pre-swizzled bf16 MFMA A/B fragments
#define WS_WK1 0
#define WS_WV1 8192
#define WS_WK2 16384
#define WS_WV2 24576
#define WS_WK3 32768
#define WS_WV3 69632
#define WS_WO  106496
#define WS_TOTAL 143360

__device__ __forceinline__ u16 f2b(float f) {
    unsigned int u; __builtin_memcpy(&u, &f, 4);
    u += 0x7FFFu + ((u >> 16) & 1u);          // round-to-nearest-even
    return (u16)(u >> 16);
}
__device__ __forceinline__ float b2f(u16 v) {
    unsigned int u = ((unsigned int)v) << 16;
    float f; __builtin_memcpy(&f, &u, 4);
    return f;
}
__device__ __forceinline__ u16x4 pack4(float4 v) {
    u16x4 o; o.x = f2b(v.x); o.y = f2b(v.y); o.z = f2b(v.z); o.w = f2b(v.w);
    return o;
}
__device__ __forceinline__ float gelu(float x) {
    float u = 0.7978845608028654f * x * (1.0f + 0.044715f * x * x);
    u = fminf(fmaxf(u, -15.0f), 15.0f);
    float e = __expf(2.0f * u);
    float t = __fdividef(e - 1.0f, e + 1.0f);  // tanh(u)
    return 0.5f * x * (1.0f + t);
}

// ---------------- weight pre-swizzle: fp32 [K x N] -> bf16 MFMA frags ----------------
// frag(mt,kt), linear f = mt*(K/32)+kt, 512 u16 each; elem(lane l, j):
//   m = mt*16 + (l&15), k = kt*32 + (l>>4)*8 + j  -> src W[k*N + m]
__global__ void prep(const float* __restrict__ Wk1, const float* __restrict__ Wk2,
                     const float* __restrict__ Wk3, const float* __restrict__ Wv1,
                     const float* __restrict__ Wv2, const float* __restrict__ Wv3,
                     const float* __restrict__ Wout, u16* __restrict__ wsw) {
    int i = blockIdx.x * 256 + threadIdx.x;
    if (i >= WS_TOTAL) return;
    const float* W; int Kd, Nd, pos;
    if      (i < WS_WV1) { W = Wk1;  Kd = 64;  Nd = 64;  pos = i; }
    else if (i < WS_WK2) { W = Wv1;  Kd = 64;  Nd = 64;  pos = i - WS_WV1; }
    else if (i < WS_WV2) { W = Wk2;  Kd = 64;  Nd = 64;  pos = i - WS_WK2; }
    else if (i < WS_WK3) { W = Wv2;  Kd = 64;  Nd = 64;  pos = i - WS_WV2; }
    else if (i < WS_WV3) { W = Wk3;  Kd = 64;  Nd = 576; pos = i - WS_WK3; }
    else if (i < WS_WO)  { W = Wv3;  Kd = 64;  Nd = 576; pos = i - WS_WV3; }
    else                 { W = Wout; Kd = 576; Nd = 64;  pos = i - WS_WO;  }
    int f = pos >> 9, rr = pos & 511, l = rr >> 3, j = rr & 7;
    int ktN = Kd >> 5;
    int mt = f / ktN, kt = f - mt * ktN;
    int m = mt * 16 + (l & 15);
    int k = kt * 32 + ((l >> 4) << 3) + j;
    wsw[i] = f2b(W[k * Nd + m]);
}

// one (mat, ct) task: D[16ch x 128e] = W^T*act, gelu, store [e][ch] bf16
__device__ __forceinline__ void mlp_layer(const u16* __restrict__ Wf,
                                          const u16* __restrict__ sin,
                                          u16* __restrict__ sout,
                                          int ct, int lane) {
    const int q = lane >> 4, el = lane & 15;
    bf16x8 a0 = *(const bf16x8*)(Wf + (ct * 2 + 0) * 512 + lane * 8);
    bf16x8 a1 = *(const bf16x8*)(Wf + (ct * 2 + 1) * 512 + lane * 8);
#pragma unroll
    for (int et = 0; et < 8; ++et) {
        const u16* br = sin + (et * 16 + el) * 72 + q * 8;
        bf16x8 b0 = *(const bf16x8*)(br);
        bf16x8 b1 = *(const bf16x8*)(br + 32);
        f32x4 c = {0.f, 0.f, 0.f, 0.f};
        c = MFMA(a0, b0, c);
        c = MFMA(a1, b1, c);
        u16x4 o;
        o.x = f2b(gelu(c[0])); o.y = f2b(gelu(c[1]));
        o.z = f2b(gelu(c[2])); o.w = f2b(gelu(c[3]));
        *(u16x4*)(sout + (et * 16 + el) * 72 + ct * 16 + q * 4) = o;
    }
}

__global__ __launch_bounds__(512, 1) void fused(
    const float* __restrict__ node_feat, const float* __restrict__ edge_sh,
    const float* __restrict__ edge_inv, const float* __restrict__ cutoff,
    const float* __restrict__ Wlogit, const int* __restrict__ edge_src,
    const u16* __restrict__ wsw, float* __restrict__ out)
{
    __shared__ __align__(16) unsigned char smem[140288];
    u16*   s_inv = (u16*)(smem);              // [128][72] bf16
    float* s_sh  = (float*)(smem + 18432);    // [128][8]
    float* s_shq = (float*)(smem + 22528);    // [128][8] sh^2
    u16*   s_h1  = (u16*)(smem + 26624);      // [2][128][72]
    u16*   s_h2  = (u16*)(smem + 63488);      // [2][128][72]
    u16*   s_x   = (u16*)(smem + 100352);     // [128][72] bf16
    float* s_q   = (float*)(smem + 118784);   // [8][64]
    float* s_cut = (float*)(smem + 120832);   // [128]
    int*   s_src = (int*)(smem + 121344);     // [128]
    float* s_lp  = (float*)(smem + 121856);   // [8][128][4] logit partials
    float* s_wgt = (float*)(smem + 138240);   // [128][4]
    u16*   s_nobf = (u16*)(smem);             // [16][584] overlay (inv+sh dead)
    float* s_no   = (float*)(smem + 26624);   // [8][576] overlay (h1 dead)

    const int tid = threadIdx.x;
    const int lane = tid & 63;
    const int w = tid >> 6;
    const int q4 = lane >> 4;     // quad
    const int el = lane & 15;
    const int blk = blockIdx.x;
    const int n0 = blk * 8;
    const long e0 = (long)blk * 128;

    // ---------------- stage ----------------
    if (tid < 128) {
        s_src[tid] = edge_src[e0 + tid];
        s_cut[tid] = cutoff[e0 + tid];
    }
    { int ln = tid >> 6, d = tid & 63;
      s_q[ln * 64 + d] = node_feat[(long)(n0 + ln) * 64 + d]; }
    { int i = tid * 2;
      float2 v = *(const float2*)(edge_sh + e0 * 8 + i);
      s_sh[i] = v.x; s_sh[i + 1] = v.y;
      s_shq[i] = v.x * v.x; s_shq[i + 1] = v.y * v.y; }
    { int row = tid >> 2, part = tid & 3;
      const float4* src = (const float4*)(edge_inv + (e0 + row) * 64) + part * 4;
      u16x4* dst = (u16x4*)(s_inv + row * 72 + part * 16);
#pragma unroll
      for (int i = 0; i < 4; ++i) dst[i] = pack4(src[i]);
    }
    __syncthreads();
    { int row = tid >> 2, part = tid & 3;
      const float4* src = (const float4*)(node_feat + (long)s_src[row] * 64) + part * 4;
      u16x4* dst = (u16x4*)(s_x + row * 72 + part * 16);
#pragma unroll
      for (int i = 0; i < 4; ++i) dst[i] = pack4(src[i]);
    }
    __syncthreads();

    // ---------------- layers 1 & 2 (k & v MLPs via MFMA) ----------------
    const int mat = w >> 2, ct12 = w & 3;
    mlp_layer(wsw + (mat ? WS_WV1 : WS_WK1), s_inv, s_h1 + mat * 9216, ct12, lane);
    __syncthreads();
    mlp_layer(wsw + (mat ? WS_WV2 : WS_WK2), s_h1 + mat * 9216, s_h2 + mat * 9216, ct12, lane);
    __syncthreads();

    // ---------------- layer 3 k-path + logits ----------------
    {
        bf16x8 ak0[5], ak1[5];
#pragma unroll
        for (int ci = 0; ci < 5; ++ci) {
            int ct = w + 8 * ci;
            if (ct < 36) {
                const u16* Af = wsw + WS_WK3 + ct * 1024 + lane * 8;
                ak0[ci] = *(const bf16x8*)(Af);
                ak1[ci] = *(const bf16x8*)(Af + 512);
            }
        }
#pragma unroll
        for (int et = 0; et < 8; ++et) {
            const u16* br = s_h2 + (et * 16 + el) * 72 + q4 * 8;
            bf16x8 b0 = *(const bf16x8*)(br);
            bf16x8 b1 = *(const bf16x8*)(br + 32);
            float L0 = 0.f, L1 = 0.f, L2 = 0.f, L3 = 0.f;
#pragma unroll
            for (int ci = 0; ci < 5; ++ci) {
                int ct = w + 8 * ci;
                if (ct < 36) {
                    f32x4 c = {0.f, 0.f, 0.f, 0.f};
                    c = MFMA(ak0[ci], b0, c);
                    c = MFMA(ak1[ci], b1, c);
                    if (ct < 4) {
                        const float* qp = s_q + et * 64 + ct * 16 + 4 * q4;
                        u16x4 xv = *(const u16x4*)(s_x + (et * 16 + el) * 72 + ct * 16 + 4 * q4);
#pragma unroll
                        for (int r = 0; r < 4; ++r) {
                            const float* wlp = Wlogit + (ct * 16 + 4 * q4 + r) * 4;
                            float wk = c[r] * qp[r] * b2f(xv[r]);
                            L0 += wk * wlp[0]; L1 += wk * wlp[1];
                            L2 += wk * wlp[2]; L3 += wk * wlp[3];
                        }
                    } else {
                        int dd = 2 * (ct - 4) + (q4 >> 1), sb = (q4 & 1) * 4;
                        float qd = s_q[et * 64 + dd];
                        float xd = b2f(s_x[(et * 16 + el) * 72 + dd]);
                        const float* sp = s_shq + (et * 16 + el) * 8 + sb;
                        float ss = c[0]*sp[0] + c[1]*sp[1] + c[2]*sp[2] + c[3]*sp[3];
                        float wk = ss * qd * xd;
                        const float* wlp = Wlogit + (64 + dd) * 4;
                        L0 += wk * wlp[0]; L1 += wk * wlp[1];
                        L2 += wk * wlp[2]; L3 += wk * wlp[3];
                    }
                }
            }
            L0 += __shfl_xor(L0, 16, 64); L0 += __shfl_xor(L0, 32, 64);
            L1 += __shfl_xor(L1, 16, 64); L1 += __shfl_xor(L1, 32, 64);
            L2 += __shfl_xor(L2, 16, 64); L2 += __shfl_xor(L2, 32, 64);
            L3 += __shfl_xor(L3, 16, 64); L3 += __shfl_xor(L3, 32, 64);
            if (lane < 16) {
                float* p = s_lp + w * 512 + (et * 16 + lane) * 4;
                p[0] = L0; p[1] = L1; p[2] = L2; p[3] = L3;
            }
        }
    }
    __syncthreads();

    // ---------------- logit reduce + softmax ----------------
    if (tid < 128) {
        float a0 = 0.f, a1 = 0.f, a2 = 0.f, a3 = 0.f;
#pragma unroll
        for (int ww = 0; ww < 8; ++ww) {
            const float* p = s_lp + ww * 512 + tid * 4;
            a0 += p[0]; a1 += p[1]; a2 += p[2]; a3 += p[3];
        }
        float* p = s_lp + tid * 4;
        p[0] = a0; p[1] = a1; p[2] = a2; p[3] = a3;
    }
    __syncthreads();
    if (tid < 32) {
        int nd = tid >> 2, h = tid & 3;
        float m = -1e30f;
#pragma unroll
        for (int e = 0; e < 16; ++e) m = fmaxf(m, s_lp[(nd * 16 + e) * 4 + h]);
        float ex[16]; float z = 0.f;
#pragma unroll
        for (int e = 0; e < 16; ++e) {
            ex[e] = s_cut[nd * 16 + e] * __expf(s_lp[(nd * 16 + e) * 4 + h] - m);
            z += ex[e];
        }
        if (z == 0.f) z = 1.f;
        float iz = __fdividef(1.f, z);
#pragma unroll
        for (int e = 0; e < 16; ++e) {
            float a = ex[e] * iz;
            s_wgt[(nd * 16 + e) * 4 + h] = sqrtf(fmaxf(a, 0.f));
        }
    }
    __syncthreads();

    // ---------------- layer 3 v-path + weighting + node reduction ----------------
    {
        bf16x8 av0[5], av1[5];
#pragma unroll
        for (int ci = 0; ci < 5; ++ci) {
            int ct = w + 8 * ci;
            if (ct < 36) {
                const u16* Af = wsw + WS_WV3 + ct * 1024 + lane * 8;
                av0[ci] = *(const bf16x8*)(Af);
                av1[ci] = *(const bf16x8*)(Af + 512);
            }
        }
#pragma unroll
        for (int et = 0; et < 8; ++et) {
            const u16* br = s_h2 + 9216 + (et * 16 + el) * 72 + q4 * 8;
            bf16x8 b0 = *(const bf16x8*)(br);
            bf16x8 b1 = *(const bf16x8*)(br + 32);
#pragma unroll
            for (int ci = 0; ci < 5; ++ci) {
                int ct = w + 8 * ci;
                if (ct < 36) {
                    f32x4 c = {0.f, 0.f, 0.f, 0.f};
                    c = MFMA(av0[ci], b0, c);
                    c = MFMA(av1[ci], b1, c);
                    int c0q = ct * 16 + 4 * q4;
                    int h = (c0q >= 432) ? 3 : (c0q >= 288) ? 2 : (c0q >= 144) ? 1 : 0;
                    float wgt = s_wgt[(et * 16 + el) * 4 + h];
                    float v0, v1, v2, v3;
                    if (ct < 4) {
                        u16x4 xv = *(const u16x4*)(s_x + (et * 16 + el) * 72 + c0q);
                        v0 = c[0] * b2f(xv[0]) * wgt;
                        v1 = c[1] * b2f(xv[1]) * wgt;
                        v2 = c[2] * b2f(xv[2]) * wgt;
                        v3 = c[3] * b2f(xv[3]) * wgt;
                    } else {
                        int dd = 2 * (ct - 4) + (q4 >> 1), sb = (q4 & 1) * 4;
                        float xd = b2f(s_x[(et * 16 + el) * 72 + dd]) * wgt;
                        const float* shp = s_sh + (et * 16 + el) * 8 + sb;
                        v0 = c[0] * xd * shp[0];
                        v1 = c[1] * xd * shp[1];
                        v2 = c[2] * xd * shp[2];
                        v3 = c[3] * xd * shp[3];
                    }
#pragma unroll
                    for (int off = 1; off < 16; off <<= 1) {
                        v0 += __shfl_xor(v0, off, 64);
                        v1 += __shfl_xor(v1, off, 64);
                        v2 += __shfl_xor(v2, off, 64);
                        v3 += __shfl_xor(v3, off, 64);
                    }
                    if (el == 0) {
                        float* p = s_no + et * 576 + c0q;
                        p[0] = v0; p[1] = v1; p[2] = v2; p[3] = v3;
                    }
                }
            }
        }
    }
    __syncthreads();

    // ---------------- node_out -> bf16 (zero-padded to 16 rows) ----------------
#pragma unroll
    for (int r = 0; r < 16; ++r)
        for (int cc = tid; cc < 576; cc += 512)
            s_nobf[r * 584 + cc] = f2b(r < 8 ? s_no[r * 576 + cc] : 0.f);
    __syncthreads();

    // ---------------- final projection via MFMA: [16n x 576] @ [576 x 64] ----------------
    if (w < 4) {
        f32x4 c = {0.f, 0.f, 0.f, 0.f};
#pragma unroll
        for (int kt = 0; kt < 18; ++kt) {
            bf16x8 a = *(const bf16x8*)(s_nobf + el * 584 + kt * 32 + q4 * 8);
            bf16x8 bb = *(const bf16x8*)(wsw + WS_WO + (w * 18 + kt) * 512 + lane * 8);
            c = MFMA(a, bb, c);
        }
        if (q4 < 2) {
#pragma unroll
            for (int r = 0; r < 4; ++r) {
                int node = q4 * 4 + r;
                out[(long)(n0 + node) * 64 + w * 16 + el] = c[r];
            }
        }
    }
}

extern "C" void kernel_launch(void* const* d_in, const int* in_sizes, int n_in,
                              void* d_out, int out_size, void* d_ws, size_t ws_size,
                              hipStream_t stream) {
    const float* node_feat = (const float*)d_in[0];
    const float* edge_sh   = (const float*)d_in[1];
    const float* edge_inv  = (const float*)d_in[2];
    const float* cutoff    = (const float*)d_in[3];
    const float* Wk1       = (const float*)d_in[4];
    const float* Wk2       = (const float*)d_in[5];
    const float* Wk3       = (const float*)d_in[6];
    const float* Wv1       = (const float*)d_in[7];
    const float* Wv2       = (const float*)d_in[8];
    const float* Wv3       = (const float*)d_in[9];
    const float* Wlogit    = (const float*)d_in[10];
    const float* Wout      = (const float*)d_in[11];
    const int*   edge_src  = (const int*)d_in[12];
    float* out = (float*)d_out;
    u16* wsw = (u16*)d_ws;

    prep<<<(WS_TOTAL + 255) / 256, 256, 0, stream>>>(
        Wk1, Wk2, Wk3, Wv1, Wv2, Wv3, Wout, wsw);
    fused<<<1024, 512, 0, stream>>>(
        node_feat, edge_sh, edge_inv, cutoff, Wlogit, edge_src, wsw, out);
}